// Round 5
// baseline (3034.458 us; speedup 1.0000x reference)
//
#include <hip/hip_runtime.h>

#define Q 16
#define SCAN_B 256

__device__ __forceinline__ float wsum(float v){
  #pragma unroll
  for(int o=32;o;o>>=1) v += __shfl_xor(v,o);
  return v;
}
__device__ __forceinline__ float wmaxr(float v){
  #pragma unroll
  for(int o=32;o;o>>=1) v = fmaxf(v,__shfl_xor(v,o));
  return v;
}

// ---- main per-iteration edge kernel: one thread per undirected edge pair ----
// In-place message update: each pair's two rows are owned by exactly one thread.
__global__ void __launch_bounds__(256) k_edge(
    const int* __restrict__ src, const int* __restrict__ dst,
    const float* msg_in, float* msg_out,
    const float* __restrict__ nl, const float* __restrict__ hc,
    const float* __restrict__ betap,
    float* __restrict__ diffpart, const int* __restrict__ donep, int M)
{
  if (*donep) return;
  const float eb = __expf(*betap) - 1.0f;
  const int p = blockIdx.x*blockDim.x + threadIdx.x;
  float dloc = 0.0f;
  if (p < M) {
    const int u = src[p], v = dst[p];
    float muv[Q], mvu[Q], hq[Q], nlu[Q], nlv[Q];
    const float4* a  = (const float4*)(msg_in + (size_t)p*Q);
    const float4* b  = (const float4*)(msg_in + ((size_t)p + (size_t)M)*Q);
    const float4* h4 = (const float4*)hc;
    const float4* u4 = (const float4*)(nl + (size_t)u*Q);
    const float4* v4 = (const float4*)(nl + (size_t)v*Q);
    #pragma unroll
    for (int i=0;i<4;i++){
      float4 t;
      t=a[i];  muv[4*i]=t.x; muv[4*i+1]=t.y; muv[4*i+2]=t.z; muv[4*i+3]=t.w;
      t=b[i];  mvu[4*i]=t.x; mvu[4*i+1]=t.y; mvu[4*i+2]=t.z; mvu[4*i+3]=t.w;
      t=h4[i]; hq [4*i]=t.x; hq [4*i+1]=t.y; hq [4*i+2]=t.z; hq [4*i+3]=t.w;
      t=u4[i]; nlu[4*i]=t.x; nlu[4*i+1]=t.y; nlu[4*i+2]=t.z; nlu[4*i+3]=t.w;
      t=v4[i]; nlv[4*i]=t.x; nlv[4*i+1]=t.y; nlv[4*i+2]=t.z; nlv[4*i+3]=t.w;
    }
    float tuv[Q], tvu[Q];
    #pragma unroll
    for (int q=0;q<Q;q++){
      float lsuv = __logf(fmaf(muv[q], eb, 1.0f));   // logS of edge u->v
      float lsvu = __logf(fmaf(mvu[q], eb, 1.0f));   // logS of edge v->u
      tuv[q] = nlu[q] - lsvu + hq[q];                // cavity for u->v removes rev (v->u)
      tvu[q] = nlv[q] - lsuv + hq[q];
    }
    float m1 = tuv[0], m2 = tvu[0];
    #pragma unroll
    for (int q=1;q<Q;q++){ m1=fmaxf(m1,tuv[q]); m2=fmaxf(m2,tvu[q]); }
    float s1=0.0f, s2=0.0f;
    #pragma unroll
    for (int q=0;q<Q;q++){
      tuv[q]=__expf(tuv[q]-m1); s1+=tuv[q];
      tvu[q]=__expf(tvu[q]-m2); s2+=tvu[q];
    }
    const float r1 = 1.0f/s1, r2 = 1.0f/s2;
    float d1=0.0f, d2=0.0f;
    #pragma unroll
    for (int q=0;q<Q;q++){
      float nuv = tuv[q]*r1, nvu = tvu[q]*r2;
      d1 += fabsf(nuv - muv[q]);
      d2 += fabsf(nvu - mvu[q]);
      muv[q]=nuv; mvu[q]=nvu;
    }
    dloc = fmaxf(d1,d2);
    float4* o1 = (float4*)(msg_out + (size_t)p*Q);
    float4* o2 = (float4*)(msg_out + ((size_t)p + (size_t)M)*Q);
    #pragma unroll
    for (int i=0;i<4;i++){
      o1[i] = make_float4(muv[4*i],muv[4*i+1],muv[4*i+2],muv[4*i+3]);
      o2[i] = make_float4(mvu[4*i],mvu[4*i+1],mvu[4*i+2],mvu[4*i+3]);
    }
  }
  // block-level max -> one plain store (no contended atomics)
  __shared__ float smx[4];
  float wm = wmaxr(dloc);
  if ((threadIdx.x & 63) == 0) smx[threadIdx.x>>6] = wm;
  __syncthreads();
  if (threadIdx.x == 0)
    diffpart[blockIdx.x] = fmaxf(fmaxf(smx[0],smx[1]), fmaxf(smx[2],smx[3]));
}

// ---- gather kernel: 4 waves/block, one wave per node; CSR over incoming edges.
// nl[n] = sum_in log1p(msg*eb); mode=1: psi=softmax(nl+h) + per-block h partials.
// 256-thread blocks: the h-partial barrier spans only 4 variable-length waves
// (1024-thr version regressed 35% from max-of-16 load imbalance).
__global__ void __launch_bounds__(256) k_gather(
    const float* __restrict__ msg, const int* __restrict__ offs,
    const int* __restrict__ eid,
    float* __restrict__ nl, const float* __restrict__ hc,
    float* __restrict__ psi, const float* __restrict__ betap,
    const int* __restrict__ donep, float* __restrict__ hpart,
    int N, int mode)
{
  if (mode && *donep) return;
  const int wid = threadIdx.x >> 6;                 // 0..3
  const int n = blockIdx.x*4 + wid;
  const float eb = __expf(*betap) - 1.0f;
  const int lane = threadIdx.x & 63;
  const int sub = lane >> 4, q = lane & 15;
  int start = 0, end = 0;
  if (n < N){ start = offs[n]; end = offs[n+1]; }
  float acc = 0.0f;
  for (int i = start + sub; i < end; i += 4){
    const int e = eid[i];
    acc += __logf(fmaf(msg[(size_t)e*Q + q], eb, 1.0f));
  }
  acc += __shfl_xor(acc, 16);
  acc += __shfl_xor(acc, 32);
  if (n < N && sub == 0) nl[(size_t)n*Q + q] = acc;
  if (!mode) return;
  float t = acc + hc[q];
  float m = t;
  #pragma unroll
  for (int o=1;o<16;o<<=1) m = fmaxf(m, __shfl_xor(m,o));
  float ex = __expf(t-m);
  float s = ex;
  #pragma unroll
  for (int o=1;o<16;o<<=1) s += __shfl_xor(s,o);
  const float pq = ex/s;
  if (n < N && sub == 0) psi[(size_t)n*Q + q] = pq;
  // per-block h column partials (psi already in registers)
  __shared__ float smh[4][17];
  if (sub == 0) smh[wid][q] = (n < N) ? pq : 0.0f;
  __syncthreads();
  if (threadIdx.x < Q)
    hpart[(size_t)blockIdx.x*Q + threadIdx.x] =
      smh[0][threadIdx.x]+smh[1][threadIdx.x]+smh[2][threadIdx.x]+smh[3][threadIdx.x];
}

// ---- per-iteration finish: h <- -beta*mean_w*colsum(hpart); done <- diff<thr ----
__global__ void __launch_bounds__(256) k_iterfin(
    const float* __restrict__ hpart, int nbh,
    const float* __restrict__ diffpart, int nbd,
    float* __restrict__ h, int* __restrict__ donep,
    const float* __restrict__ betap, float mean_w)
{
  if (*donep) return;
  const int t = threadIdx.x, g = t>>4, q = t&15;
  float s = 0.0f;
  for (int b = g; b < nbh; b += 16) s += hpart[(size_t)b*Q + q];
  __shared__ float sm[16][17];
  sm[g][q] = s; __syncthreads();
  if (t < Q){
    float tot = 0.0f;
    #pragma unroll
    for (int i=0;i<16;i++) tot += sm[i][t];
    h[t] = -(*betap) * mean_w * tot;
  }
  float m = 0.0f;
  for (int i = t; i < nbd; i += 256) m = fmaxf(m, diffpart[i]);
  m = wmaxr(m);
  __shared__ float red[4];
  if ((t & 63) == 0) red[t>>6] = m;
  __syncthreads();
  if (t == 0 &&
      fmaxf(fmaxf(red[0],red[1]), fmaxf(red[2],red[3])) < 0.01f) *donep = 1;
}

// ---- h partials over psi0 (init only) ----
__global__ void __launch_bounds__(256) k_h_part(
    const float* __restrict__ psi, float* __restrict__ hpart, int N)
{
  const int n = blockIdx.x*blockDim.x + threadIdx.x;
  float pv[Q];
  if (n < N) {
    const float4* a = (const float4*)(psi + (size_t)n*Q);
    #pragma unroll
    for (int i=0;i<4;i++){ float4 t=a[i]; pv[4*i]=t.x; pv[4*i+1]=t.y; pv[4*i+2]=t.z; pv[4*i+3]=t.w; }
  } else {
    #pragma unroll
    for (int q=0;q<Q;q++) pv[q]=0.0f;
  }
  __shared__ float sm[4][Q];
  const int wid = threadIdx.x>>6, lane = threadIdx.x&63;
  #pragma unroll
  for (int q=0;q<Q;q++){
    float s = wsum(pv[q]);
    if (lane == 0) sm[wid][q] = s;
  }
  __syncthreads();
  if (threadIdx.x < Q)
    hpart[(size_t)blockIdx.x*Q + threadIdx.x] =
      sm[0][threadIdx.x]+sm[1][threadIdx.x]+sm[2][threadIdx.x]+sm[3][threadIdx.x];
}

__global__ void __launch_bounds__(256) k_hfin(
    const float* __restrict__ hpart, float* __restrict__ h,
    const float* __restrict__ betap, int nb, float mean_w)
{
  const int t = threadIdx.x, g = t>>4, q = t&15;
  float s = 0.0f;
  for (int b = g; b < nb; b += 16) s += hpart[(size_t)b*Q + q];
  __shared__ float sm[16][17];
  sm[g][q] = s; __syncthreads();
  if (t < Q){
    float tot = 0.0f;
    #pragma unroll
    for (int i=0;i<16;i++) tot += sm[i][t];
    h[t] = -(*betap) * mean_w * tot;
  }
}

// ---- CSR build ----
__global__ void __launch_bounds__(256) k_deg(
    const int* __restrict__ dst, int* __restrict__ deg, int E)
{
  const int e = blockIdx.x*blockDim.x + threadIdx.x;
  if (e < E) atomicAdd(&deg[dst[e]], 1);
}

__global__ void __launch_bounds__(SCAN_B) k_scan1(
    const int* __restrict__ deg, int* __restrict__ offs,
    int* __restrict__ bsum, int N)
{
  __shared__ int sm[SCAN_B];
  const int i = blockIdx.x*SCAN_B + threadIdx.x;
  const int v = (i<N) ? deg[i] : 0;
  sm[threadIdx.x] = v; __syncthreads();
  #pragma unroll
  for (int o=1;o<SCAN_B;o<<=1){
    int t = (threadIdx.x>=o) ? sm[threadIdx.x-o] : 0;
    __syncthreads();
    sm[threadIdx.x] += t;
    __syncthreads();
  }
  if (i<N) offs[i] = sm[threadIdx.x] - v;           // block-local exclusive
  if (threadIdx.x==SCAN_B-1) bsum[blockIdx.x] = sm[threadIdx.x];
}

__global__ void __launch_bounds__(SCAN_B) k_scan2(int* __restrict__ bsum, int nb)
{
  __shared__ int sm[SCAN_B];
  const int v = (threadIdx.x<nb) ? bsum[threadIdx.x] : 0;
  sm[threadIdx.x] = v; __syncthreads();
  #pragma unroll
  for (int o=1;o<SCAN_B;o<<=1){
    int t = (threadIdx.x>=o) ? sm[threadIdx.x-o] : 0;
    __syncthreads();
    sm[threadIdx.x] += t;
    __syncthreads();
  }
  if (threadIdx.x<nb) bsum[threadIdx.x] = sm[threadIdx.x] - v;  // exclusive
}

__global__ void __launch_bounds__(SCAN_B) k_scan3(
    int* __restrict__ offs, int* __restrict__ cursor,
    const int* __restrict__ bsum, int N, int E)
{
  const int i = blockIdx.x*SCAN_B + threadIdx.x;
  if (i<N){
    const int o = offs[i] + bsum[blockIdx.x];
    offs[i] = o; cursor[i] = o;
  }
  if (i==0) offs[N] = E;
}

__global__ void __launch_bounds__(256) k_fill(
    const int* __restrict__ dst, int* __restrict__ cursor,
    int* __restrict__ eid, int E)
{
  const int e = blockIdx.x*blockDim.x + threadIdx.x;
  if (e < E){
    const int p = atomicAdd(&cursor[dst[e]], 1);
    eid[p] = e;
  }
}

// ---- finalization: per-block partials, no atomics ----
__global__ void __launch_bounds__(256) k_edge_term(
    const int* __restrict__ src, const int* __restrict__ dst,
    const float* __restrict__ psi, float* __restrict__ edgepart, int M)
{
  const int p = blockIdx.x*blockDim.x + threadIdx.x;
  float d = 0.0f;
  if (p < M) {
    const int u = src[p], v = dst[p];
    const float4* a = (const float4*)(psi + (size_t)u*Q);
    const float4* b = (const float4*)(psi + (size_t)v*Q);
    #pragma unroll
    for (int i=0;i<4;i++){
      float4 x=a[i], y=b[i];
      d += x.x*y.x + x.y*y.y + x.z*y.z + x.w*y.w;
    }
    d *= 2.0f;   // each pair appears twice in the directed edge list
  }
  float s = wsum(d);
  __shared__ float sm[4];
  if ((threadIdx.x & 63) == 0) sm[threadIdx.x>>6] = s;
  __syncthreads();
  if (threadIdx.x == 0) edgepart[blockIdx.x] = sm[0]+sm[1]+sm[2]+sm[3];
}

__global__ void __launch_bounds__(256) k_node_stats(
    const float* __restrict__ psi, const int* __restrict__ deg,
    float* __restrict__ colpart, float* __restrict__ degpart,
    float* __restrict__ entpart, int N)
{
  const int n = blockIdx.x*blockDim.x + threadIdx.x;
  float pv[Q]; float dg = 0.0f; float ent = 0.0f;
  if (n < N) {
    const float4* a = (const float4*)(psi + (size_t)n*Q);
    #pragma unroll
    for (int i=0;i<4;i++){ float4 t=a[i]; pv[4*i]=t.x; pv[4*i+1]=t.y; pv[4*i+2]=t.z; pv[4*i+3]=t.w; }
    dg = (float)deg[n];
    #pragma unroll
    for (int q=0;q<Q;q++) ent -= pv[q]*__logf(pv[q]+1e-12f);
  } else {
    #pragma unroll
    for (int q=0;q<Q;q++) pv[q]=0.0f;
  }
  __shared__ float smc[4][Q], smd[4][Q], sme[4];
  const int wid = threadIdx.x>>6, lane = threadIdx.x&63;
  #pragma unroll
  for (int q=0;q<Q;q++){
    float s  = wsum(pv[q]);
    float s2 = wsum(pv[q]*dg);
    if (lane == 0){ smc[wid][q]=s; smd[wid][q]=s2; }
  }
  float se = wsum(ent);
  if (lane == 0) sme[wid] = se;
  __syncthreads();
  if (threadIdx.x < Q){
    colpart[(size_t)blockIdx.x*Q+threadIdx.x] =
      smc[0][threadIdx.x]+smc[1][threadIdx.x]+smc[2][threadIdx.x]+smc[3][threadIdx.x];
    degpart[(size_t)blockIdx.x*Q+threadIdx.x] =
      smd[0][threadIdx.x]+smd[1][threadIdx.x]+smd[2][threadIdx.x]+smd[3][threadIdx.x];
  }
  if (threadIdx.x == 0) entpart[blockIdx.x] = sme[0]+sme[1]+sme[2]+sme[3];
}

__global__ void __launch_bounds__(256) k_finalize(
    const float* __restrict__ edgepart, int ne,
    const float* __restrict__ colpart, const float* __restrict__ degpart,
    const float* __restrict__ entpart, int nbn,
    float* __restrict__ out, int N, float m2, int NQ)
{
  __shared__ float sm[16][Q];
  __shared__ float red[4];
  const int t = threadIdx.x, g = t>>4, q = t&15;
  float cs=0.0f, ds=0.0f;
  for (int b=g; b<nbn; b+=16){ cs += colpart[(size_t)b*Q+q]; ds += degpart[(size_t)b*Q+q]; }
  sm[g][q] = cs; __syncthreads();
  float colq = 0.0f;
  if (t < Q){ for (int i=0;i<16;i++) colq += sm[i][t]; }
  __syncthreads();
  sm[g][q] = ds; __syncthreads();
  float degq = 0.0f;
  if (t < Q){ for (int i=0;i<16;i++) degq += sm[i][t]; }
  __syncthreads();
  float es = 0.0f;
  for (int i=t; i<ne; i+=256) es += edgepart[i];
  es = wsum(es);
  if ((t&63)==0) red[t>>6] = es;
  __syncthreads();
  const float edge_total = red[0]+red[1]+red[2]+red[3];
  __syncthreads();
  float en = 0.0f;
  for (int i=t; i<nbn; i+=256) en += entpart[i];
  en = wsum(en);
  if ((t&63)==0) red[t>>6] = en;
  __syncthreads();
  const float ent_total = red[0]+red[1]+red[2]+red[3];
  __syncthreads();
  if (t < Q){ sm[0][t] = colq; sm[1][t] = degq; }
  __syncthreads();
  if (t == 0){
    float reg = 0.0f, dt = 0.0f;
    for (int i=0;i<Q;i++){
      float d = sm[0][i]/(float)N - 1.0f/(float)Q; reg += d*d;
      float s = sm[1][i]/m2; dt += s*s;
    }
    out[NQ+0] = reg * 4.0f;                                // * sqrt(16)
    out[NQ+1] = ent_total/(float)N / 2.7725887222397811f;  // / log(16)
    out[NQ+2] = edge_total/m2 - dt;
  }
}

extern "C" void kernel_launch(void* const* d_in, const int* in_sizes, int n_in,
                              void* d_out, int out_size, void* d_ws, size_t ws_size,
                              hipStream_t stream)
{
  const int*   src   = (const int*)  d_in[0];
  const int*   dst   = (const int*)  d_in[1];
  // d_in[2] = rev : structurally rev[p]=p+M / p-M, exploited directly
  const float* psi0  = (const float*)d_in[3];
  const float* msg0  = (const float*)d_in[4];
  const float* betap = (const float*)d_in[5];

  const int E  = in_sizes[0];
  const int M  = E/2;
  const int NQ = in_sizes[3];
  const int N  = NQ/Q;
  const float mean_w = (float)((double)E/((double)N*(double)N));
  const float m2 = (float)E;

  const int B = 256;
  const int gE = (E+B-1)/B, gM = (M+B-1)/B, gN = (N+B-1)/B;
  const int nb = (N+SCAN_B-1)/SCAN_B;
  const int gW = (N+3)/4;                        // 4 nodes per 256-thr block

  char* w = (char*)d_ws;
  float* msgA    = (float*)w; w += (size_t)E*Q*sizeof(float);
  float* nl      = (float*)w; w += (size_t)NQ*sizeof(float);
  int*   eid     = (int*)  w; w += (size_t)E*sizeof(int);
  int*   offs    = (int*)  w; w += (size_t)(N+16)*sizeof(int);
  int*   cursor  = (int*)  w; w += (size_t)(N+16)*sizeof(int);
  int*   bsum    = (int*)  w; w += 256*sizeof(int);
  float* hpart   = (float*)w; w += (size_t)gW*Q*sizeof(float);   // also init partials (gN<gW)
  float* diffpart= (float*)w; w += (size_t)gM*sizeof(float);
  float* edgepart= (float*)w; w += (size_t)gM*sizeof(float);
  float* colpart = (float*)w; w += (size_t)gN*Q*sizeof(float);
  float* degpart = (float*)w; w += (size_t)gN*Q*sizeof(float);
  float* entpart = (float*)w; w += (size_t)gN*sizeof(float);
  int*   deg     = (int*)  w; w += (size_t)(N+16)*sizeof(int);   // memset from here
  float* h       = (float*)w; w += 16*sizeof(float);
  int*   donep   = (int*)  w; w += 4*sizeof(int);

  float* psi = (float*)d_out;   // [N,Q]; scalars at NQ..NQ+2

  const size_t small_bytes = (size_t)((char*)w - (char*)deg);
  hipMemsetAsync(deg, 0, small_bytes, stream);   // deg, h, done

  // one-time: h0, CSR build, initial node_log
  k_h_part<<<gN,B,0,stream>>>(psi0, hpart, N);
  k_hfin  <<<1, B,0,stream>>>(hpart, h, betap, gN, mean_w);
  k_deg   <<<gE,B,0,stream>>>(dst, deg, E);
  k_scan1 <<<nb,SCAN_B,0,stream>>>(deg, offs, bsum, N);
  k_scan2 <<<1, SCAN_B,0,stream>>>(bsum, nb);
  k_scan3 <<<nb,SCAN_B,0,stream>>>(offs, cursor, bsum, N, E);
  k_fill  <<<gE,B,0,stream>>>(dst, cursor, eid, E);
  k_gather<<<gW,B,0,stream>>>(msg0, offs, eid, nl, h, psi, betap, donep, hpart, N, 0);

  for (int k=0; k<10; ++k) {
    const float* mc = (k==0) ? msg0 : msgA;
    k_edge   <<<gM,B,0,stream>>>(src, dst, mc, msgA, nl, h, betap, diffpart, donep, M);
    k_gather <<<gW,B,0,stream>>>(msgA, offs, eid, nl, h, psi, betap, donep, hpart, N, 1);
    k_iterfin<<<1, B,0,stream>>>(hpart, gW, diffpart, gM, h, donep, betap, mean_w);
  }

  k_edge_term <<<gM,B,0,stream>>>(src, dst, psi, edgepart, M);
  k_node_stats<<<gN,B,0,stream>>>(psi, deg, colpart, degpart, entpart, N);
  k_finalize  <<<1,B,0,stream>>>(edgepart, gM, colpart, degpart, entpart, gN,
                                 psi, N, m2, NQ);
}

// Round 6
// 1228.487 us; speedup vs baseline: 2.4701x; 2.4701x over previous
//
#include <hip/hip_runtime.h>

#define Q 16
#define SCAN_B 256

__device__ __forceinline__ float wsum(float v){
  #pragma unroll
  for(int o=32;o;o>>=1) v += __shfl_xor(v,o);
  return v;
}
__device__ __forceinline__ float wmaxr(float v){
  #pragma unroll
  for(int o=32;o;o>>=1) v = fmaxf(v,__shfl_xor(v,o));
  return v;
}

// ---- main per-iteration edge kernel: one thread per undirected edge pair ----
// In-place message update: each pair's two rows are owned by exactly one thread.
__global__ void __launch_bounds__(256) k_edge(
    const int* __restrict__ src, const int* __restrict__ dst,
    const float* msg_in, float* msg_out,
    const float* __restrict__ nl, const float* __restrict__ hc,
    const float* __restrict__ betap,
    float* __restrict__ diffpart, const int* __restrict__ donep, int M)
{
  if (*donep) return;
  const float eb = __expf(*betap) - 1.0f;
  const int p = blockIdx.x*blockDim.x + threadIdx.x;
  float dloc = 0.0f;
  if (p < M) {
    const int u = src[p], v = dst[p];
    float muv[Q], mvu[Q], hq[Q], nlu[Q], nlv[Q];
    const float4* a  = (const float4*)(msg_in + (size_t)p*Q);
    const float4* b  = (const float4*)(msg_in + ((size_t)p + (size_t)M)*Q);
    const float4* h4 = (const float4*)hc;
    const float4* u4 = (const float4*)(nl + (size_t)u*Q);
    const float4* v4 = (const float4*)(nl + (size_t)v*Q);
    #pragma unroll
    for (int i=0;i<4;i++){
      float4 t;
      t=a[i];  muv[4*i]=t.x; muv[4*i+1]=t.y; muv[4*i+2]=t.z; muv[4*i+3]=t.w;
      t=b[i];  mvu[4*i]=t.x; mvu[4*i+1]=t.y; mvu[4*i+2]=t.z; mvu[4*i+3]=t.w;
      t=h4[i]; hq [4*i]=t.x; hq [4*i+1]=t.y; hq [4*i+2]=t.z; hq [4*i+3]=t.w;
      t=u4[i]; nlu[4*i]=t.x; nlu[4*i+1]=t.y; nlu[4*i+2]=t.z; nlu[4*i+3]=t.w;
      t=v4[i]; nlv[4*i]=t.x; nlv[4*i+1]=t.y; nlv[4*i+2]=t.z; nlv[4*i+3]=t.w;
    }
    float tuv[Q], tvu[Q];
    #pragma unroll
    for (int q=0;q<Q;q++){
      float lsuv = __logf(fmaf(muv[q], eb, 1.0f));   // logS of edge u->v
      float lsvu = __logf(fmaf(mvu[q], eb, 1.0f));   // logS of edge v->u
      tuv[q] = nlu[q] - lsvu + hq[q];                // cavity for u->v removes rev (v->u)
      tvu[q] = nlv[q] - lsuv + hq[q];
    }
    float m1 = tuv[0], m2 = tvu[0];
    #pragma unroll
    for (int q=1;q<Q;q++){ m1=fmaxf(m1,tuv[q]); m2=fmaxf(m2,tvu[q]); }
    float s1=0.0f, s2=0.0f;
    #pragma unroll
    for (int q=0;q<Q;q++){
      tuv[q]=__expf(tuv[q]-m1); s1+=tuv[q];
      tvu[q]=__expf(tvu[q]-m2); s2+=tvu[q];
    }
    const float r1 = 1.0f/s1, r2 = 1.0f/s2;
    float d1=0.0f, d2=0.0f;
    #pragma unroll
    for (int q=0;q<Q;q++){
      float nuv = tuv[q]*r1, nvu = tvu[q]*r2;
      d1 += fabsf(nuv - muv[q]);
      d2 += fabsf(nvu - mvu[q]);
      muv[q]=nuv; mvu[q]=nvu;
    }
    dloc = fmaxf(d1,d2);
    float4* o1 = (float4*)(msg_out + (size_t)p*Q);
    float4* o2 = (float4*)(msg_out + ((size_t)p + (size_t)M)*Q);
    #pragma unroll
    for (int i=0;i<4;i++){
      o1[i] = make_float4(muv[4*i],muv[4*i+1],muv[4*i+2],muv[4*i+3]);
      o2[i] = make_float4(mvu[4*i],mvu[4*i+1],mvu[4*i+2],mvu[4*i+3]);
    }
  }
  // block-level max -> one plain store (no contended atomics)
  __shared__ float smx[4];
  float wm = wmaxr(dloc);
  if ((threadIdx.x & 63) == 0) smx[threadIdx.x>>6] = wm;
  __syncthreads();
  if (threadIdx.x == 0)
    diffpart[blockIdx.x] = fmaxf(fmaxf(smx[0],smx[1]), fmaxf(smx[2],smx[3]));
}

// ---- gather kernel: 4 waves/block, one wave per node; CSR over incoming edges.
// nl[n] = sum_in log1p(msg*eb); mode=1: psi=softmax(nl+h) + per-block h partials.
__global__ void __launch_bounds__(256) k_gather(
    const float* __restrict__ msg, const int* __restrict__ offs,
    const int* __restrict__ eid,
    float* __restrict__ nl, const float* __restrict__ hc,
    float* __restrict__ psi, const float* __restrict__ betap,
    const int* __restrict__ donep, float* __restrict__ hpart,
    int N, int mode)
{
  if (mode && *donep) return;
  const int wid = threadIdx.x >> 6;                 // 0..3
  const int n = blockIdx.x*4 + wid;
  const float eb = __expf(*betap) - 1.0f;
  const int lane = threadIdx.x & 63;
  const int sub = lane >> 4, q = lane & 15;
  int start = 0, end = 0;
  if (n < N){ start = offs[n]; end = offs[n+1]; }
  float acc = 0.0f;
  for (int i = start + sub; i < end; i += 4){
    const int e = eid[i];
    acc += __logf(fmaf(msg[(size_t)e*Q + q], eb, 1.0f));
  }
  acc += __shfl_xor(acc, 16);
  acc += __shfl_xor(acc, 32);
  if (n < N && sub == 0) nl[(size_t)n*Q + q] = acc;
  if (!mode) return;
  float t = acc + hc[q];
  float m = t;
  #pragma unroll
  for (int o=1;o<16;o<<=1) m = fmaxf(m, __shfl_xor(m,o));
  float ex = __expf(t-m);
  float s = ex;
  #pragma unroll
  for (int o=1;o<16;o<<=1) s += __shfl_xor(s,o);
  const float pq = ex/s;
  if (n < N && sub == 0) psi[(size_t)n*Q + q] = pq;
  // per-block h column partials (psi already in registers)
  __shared__ float smh[4][17];
  if (sub == 0) smh[wid][q] = (n < N) ? pq : 0.0f;
  __syncthreads();
  if (threadIdx.x < Q)
    hpart[(size_t)blockIdx.x*Q + threadIdx.x] =
      smh[0][threadIdx.x]+smh[1][threadIdx.x]+smh[2][threadIdx.x]+smh[3][threadIdx.x];
}

// ---- intermediate h reduce: each block collapses 256 hpart rows into one ----
// (single-block k_iterfin scanning 800KB was 195us/iter in R5 — KB-scale only)
__global__ void __launch_bounds__(256) k_hred(
    const float* __restrict__ hpart, int nrows,
    float* __restrict__ hpart2, const int* __restrict__ donep)
{
  if (*donep) return;
  const int g = threadIdx.x>>4, q = threadIdx.x&15;
  const int base = blockIdx.x*256;
  const int lim = min(base+256, nrows);
  float s = 0.0f;
  for (int r = base+g; r < lim; r += 16) s += hpart[(size_t)r*Q + q];
  __shared__ float sm[16][17];
  sm[g][q] = s; __syncthreads();
  if (threadIdx.x < Q){
    float tot = 0.0f;
    #pragma unroll
    for (int i=0;i<16;i++) tot += sm[i][threadIdx.x];
    hpart2[(size_t)blockIdx.x*Q + threadIdx.x] = tot;
  }
}

// ---- per-iteration finish: h <- -beta*mean_w*colsum(hpart2); done <- diff<thr ----
__global__ void __launch_bounds__(256) k_iterfin(
    const float* __restrict__ hpart, int nbh,
    const float* __restrict__ diffpart, int nbd,
    float* __restrict__ h, int* __restrict__ donep,
    const float* __restrict__ betap, float mean_w)
{
  if (*donep) return;
  const int t = threadIdx.x, g = t>>4, q = t&15;
  float s = 0.0f;
  for (int b = g; b < nbh; b += 16) s += hpart[(size_t)b*Q + q];
  __shared__ float sm[16][17];
  sm[g][q] = s; __syncthreads();
  if (t < Q){
    float tot = 0.0f;
    #pragma unroll
    for (int i=0;i<16;i++) tot += sm[i][t];
    h[t] = -(*betap) * mean_w * tot;
  }
  float m = 0.0f;
  for (int i = t; i < nbd; i += 256) m = fmaxf(m, diffpart[i]);
  m = wmaxr(m);
  __shared__ float red[4];
  if ((t & 63) == 0) red[t>>6] = m;
  __syncthreads();
  if (t == 0 &&
      fmaxf(fmaxf(red[0],red[1]), fmaxf(red[2],red[3])) < 0.01f) *donep = 1;
}

// ---- h partials over psi0 (init only) ----
__global__ void __launch_bounds__(256) k_h_part(
    const float* __restrict__ psi, float* __restrict__ hpart, int N)
{
  const int n = blockIdx.x*blockDim.x + threadIdx.x;
  float pv[Q];
  if (n < N) {
    const float4* a = (const float4*)(psi + (size_t)n*Q);
    #pragma unroll
    for (int i=0;i<4;i++){ float4 t=a[i]; pv[4*i]=t.x; pv[4*i+1]=t.y; pv[4*i+2]=t.z; pv[4*i+3]=t.w; }
  } else {
    #pragma unroll
    for (int q=0;q<Q;q++) pv[q]=0.0f;
  }
  __shared__ float sm[4][Q];
  const int wid = threadIdx.x>>6, lane = threadIdx.x&63;
  #pragma unroll
  for (int q=0;q<Q;q++){
    float s = wsum(pv[q]);
    if (lane == 0) sm[wid][q] = s;
  }
  __syncthreads();
  if (threadIdx.x < Q)
    hpart[(size_t)blockIdx.x*Q + threadIdx.x] =
      sm[0][threadIdx.x]+sm[1][threadIdx.x]+sm[2][threadIdx.x]+sm[3][threadIdx.x];
}

__global__ void __launch_bounds__(256) k_hfin(
    const float* __restrict__ hpart, float* __restrict__ h,
    const float* __restrict__ betap, int nb, float mean_w)
{
  const int t = threadIdx.x, g = t>>4, q = t&15;
  float s = 0.0f;
  for (int b = g; b < nb; b += 16) s += hpart[(size_t)b*Q + q];
  __shared__ float sm[16][17];
  sm[g][q] = s; __syncthreads();
  if (t < Q){
    float tot = 0.0f;
    #pragma unroll
    for (int i=0;i<16;i++) tot += sm[i][t];
    h[t] = -(*betap) * mean_w * tot;
  }
}

// ---- CSR build ----
__global__ void __launch_bounds__(256) k_deg(
    const int* __restrict__ dst, int* __restrict__ deg, int E)
{
  const int e = blockIdx.x*blockDim.x + threadIdx.x;
  if (e < E) atomicAdd(&deg[dst[e]], 1);
}

__global__ void __launch_bounds__(SCAN_B) k_scan1(
    const int* __restrict__ deg, int* __restrict__ offs,
    int* __restrict__ bsum, int N)
{
  __shared__ int sm[SCAN_B];
  const int i = blockIdx.x*SCAN_B + threadIdx.x;
  const int v = (i<N) ? deg[i] : 0;
  sm[threadIdx.x] = v; __syncthreads();
  #pragma unroll
  for (int o=1;o<SCAN_B;o<<=1){
    int t = (threadIdx.x>=o) ? sm[threadIdx.x-o] : 0;
    __syncthreads();
    sm[threadIdx.x] += t;
    __syncthreads();
  }
  if (i<N) offs[i] = sm[threadIdx.x] - v;           // block-local exclusive
  if (threadIdx.x==SCAN_B-1) bsum[blockIdx.x] = sm[threadIdx.x];
}

__global__ void __launch_bounds__(SCAN_B) k_scan2(int* __restrict__ bsum, int nb)
{
  __shared__ int sm[SCAN_B];
  const int v = (threadIdx.x<nb) ? bsum[threadIdx.x] : 0;
  sm[threadIdx.x] = v; __syncthreads();
  #pragma unroll
  for (int o=1;o<SCAN_B;o<<=1){
    int t = (threadIdx.x>=o) ? sm[threadIdx.x-o] : 0;
    __syncthreads();
    sm[threadIdx.x] += t;
    __syncthreads();
  }
  if (threadIdx.x<nb) bsum[threadIdx.x] = sm[threadIdx.x] - v;  // exclusive
}

__global__ void __launch_bounds__(SCAN_B) k_scan3(
    int* __restrict__ offs, int* __restrict__ cursor,
    const int* __restrict__ bsum, int N, int E)
{
  const int i = blockIdx.x*SCAN_B + threadIdx.x;
  if (i<N){
    const int o = offs[i] + bsum[blockIdx.x];
    offs[i] = o; cursor[i] = o;
  }
  if (i==0) offs[N] = E;
}

__global__ void __launch_bounds__(256) k_fill(
    const int* __restrict__ dst, int* __restrict__ cursor,
    int* __restrict__ eid, int E)
{
  const int e = blockIdx.x*blockDim.x + threadIdx.x;
  if (e < E){
    const int p = atomicAdd(&cursor[dst[e]], 1);
    eid[p] = e;
  }
}

// ---- finalization: per-block partials, no atomics ----
__global__ void __launch_bounds__(256) k_edge_term(
    const int* __restrict__ src, const int* __restrict__ dst,
    const float* __restrict__ psi, float* __restrict__ edgepart, int M)
{
  const int p = blockIdx.x*blockDim.x + threadIdx.x;
  float d = 0.0f;
  if (p < M) {
    const int u = src[p], v = dst[p];
    const float4* a = (const float4*)(psi + (size_t)u*Q);
    const float4* b = (const float4*)(psi + (size_t)v*Q);
    #pragma unroll
    for (int i=0;i<4;i++){
      float4 x=a[i], y=b[i];
      d += x.x*y.x + x.y*y.y + x.z*y.z + x.w*y.w;
    }
    d *= 2.0f;   // each pair appears twice in the directed edge list
  }
  float s = wsum(d);
  __shared__ float sm[4];
  if ((threadIdx.x & 63) == 0) sm[threadIdx.x>>6] = s;
  __syncthreads();
  if (threadIdx.x == 0) edgepart[blockIdx.x] = sm[0]+sm[1]+sm[2]+sm[3];
}

__global__ void __launch_bounds__(256) k_node_stats(
    const float* __restrict__ psi, const int* __restrict__ deg,
    float* __restrict__ colpart, float* __restrict__ degpart,
    float* __restrict__ entpart, int N)
{
  const int n = blockIdx.x*blockDim.x + threadIdx.x;
  float pv[Q]; float dg = 0.0f; float ent = 0.0f;
  if (n < N) {
    const float4* a = (const float4*)(psi + (size_t)n*Q);
    #pragma unroll
    for (int i=0;i<4;i++){ float4 t=a[i]; pv[4*i]=t.x; pv[4*i+1]=t.y; pv[4*i+2]=t.z; pv[4*i+3]=t.w; }
    dg = (float)deg[n];
    #pragma unroll
    for (int q=0;q<Q;q++) ent -= pv[q]*__logf(pv[q]+1e-12f);
  } else {
    #pragma unroll
    for (int q=0;q<Q;q++) pv[q]=0.0f;
  }
  __shared__ float smc[4][Q], smd[4][Q], sme[4];
  const int wid = threadIdx.x>>6, lane = threadIdx.x&63;
  #pragma unroll
  for (int q=0;q<Q;q++){
    float s  = wsum(pv[q]);
    float s2 = wsum(pv[q]*dg);
    if (lane == 0){ smc[wid][q]=s; smd[wid][q]=s2; }
  }
  float se = wsum(ent);
  if (lane == 0) sme[wid] = se;
  __syncthreads();
  if (threadIdx.x < Q){
    colpart[(size_t)blockIdx.x*Q+threadIdx.x] =
      smc[0][threadIdx.x]+smc[1][threadIdx.x]+smc[2][threadIdx.x]+smc[3][threadIdx.x];
    degpart[(size_t)blockIdx.x*Q+threadIdx.x] =
      smd[0][threadIdx.x]+smd[1][threadIdx.x]+smd[2][threadIdx.x]+smd[3][threadIdx.x];
  }
  if (threadIdx.x == 0) entpart[blockIdx.x] = sme[0]+sme[1]+sme[2]+sme[3];
}

__global__ void __launch_bounds__(256) k_finalize(
    const float* __restrict__ edgepart, int ne,
    const float* __restrict__ colpart, const float* __restrict__ degpart,
    const float* __restrict__ entpart, int nbn,
    float* __restrict__ out, int N, float m2, int NQ)
{
  __shared__ float sm[16][Q];
  __shared__ float red[4];
  const int t = threadIdx.x, g = t>>4, q = t&15;
  float cs=0.0f, ds=0.0f;
  for (int b=g; b<nbn; b+=16){ cs += colpart[(size_t)b*Q+q]; ds += degpart[(size_t)b*Q+q]; }
  sm[g][q] = cs; __syncthreads();
  float colq = 0.0f;
  if (t < Q){ for (int i=0;i<16;i++) colq += sm[i][t]; }
  __syncthreads();
  sm[g][q] = ds; __syncthreads();
  float degq = 0.0f;
  if (t < Q){ for (int i=0;i<16;i++) degq += sm[i][t]; }
  __syncthreads();
  float es = 0.0f;
  for (int i=t; i<ne; i+=256) es += edgepart[i];
  es = wsum(es);
  if ((t&63)==0) red[t>>6] = es;
  __syncthreads();
  const float edge_total = red[0]+red[1]+red[2]+red[3];
  __syncthreads();
  float en = 0.0f;
  for (int i=t; i<nbn; i+=256) en += entpart[i];
  en = wsum(en);
  if ((t&63)==0) red[t>>6] = en;
  __syncthreads();
  const float ent_total = red[0]+red[1]+red[2]+red[3];
  __syncthreads();
  if (t < Q){ sm[0][t] = colq; sm[1][t] = degq; }
  __syncthreads();
  if (t == 0){
    float reg = 0.0f, dt = 0.0f;
    for (int i=0;i<Q;i++){
      float d = sm[0][i]/(float)N - 1.0f/(float)Q; reg += d*d;
      float s = sm[1][i]/m2; dt += s*s;
    }
    out[NQ+0] = reg * 4.0f;                                // * sqrt(16)
    out[NQ+1] = ent_total/(float)N / 2.7725887222397811f;  // / log(16)
    out[NQ+2] = edge_total/m2 - dt;
  }
}

extern "C" void kernel_launch(void* const* d_in, const int* in_sizes, int n_in,
                              void* d_out, int out_size, void* d_ws, size_t ws_size,
                              hipStream_t stream)
{
  const int*   src   = (const int*)  d_in[0];
  const int*   dst   = (const int*)  d_in[1];
  // d_in[2] = rev : structurally rev[p]=p+M / p-M, exploited directly
  const float* psi0  = (const float*)d_in[3];
  const float* msg0  = (const float*)d_in[4];
  const float* betap = (const float*)d_in[5];

  const int E  = in_sizes[0];
  const int M  = E/2;
  const int NQ = in_sizes[3];
  const int N  = NQ/Q;
  const float mean_w = (float)((double)E/((double)N*(double)N));
  const float m2 = (float)E;

  const int B = 256;
  const int gE = (E+B-1)/B, gM = (M+B-1)/B, gN = (N+B-1)/B;
  const int nb = (N+SCAN_B-1)/SCAN_B;
  const int gW = (N+3)/4;                        // 4 nodes per 256-thr block
  const int gH = (gW+255)/256;                   // hred blocks (~49)

  char* w = (char*)d_ws;
  float* msgA    = (float*)w; w += (size_t)E*Q*sizeof(float);
  float* nl      = (float*)w; w += (size_t)NQ*sizeof(float);
  int*   eid     = (int*)  w; w += (size_t)E*sizeof(int);
  int*   offs    = (int*)  w; w += (size_t)(N+16)*sizeof(int);
  int*   cursor  = (int*)  w; w += (size_t)(N+16)*sizeof(int);
  int*   bsum    = (int*)  w; w += 256*sizeof(int);
  float* hpart   = (float*)w; w += (size_t)gW*Q*sizeof(float);   // also init partials (gN<gW)
  float* hpart2  = (float*)w; w += (size_t)gH*Q*sizeof(float);
  float* diffpart= (float*)w; w += (size_t)gM*sizeof(float);
  float* edgepart= (float*)w; w += (size_t)gM*sizeof(float);
  float* colpart = (float*)w; w += (size_t)gN*Q*sizeof(float);
  float* degpart = (float*)w; w += (size_t)gN*Q*sizeof(float);
  float* entpart = (float*)w; w += (size_t)gN*sizeof(float);
  int*   deg     = (int*)  w; w += (size_t)(N+16)*sizeof(int);   // memset from here
  float* h       = (float*)w; w += 16*sizeof(float);
  int*   donep   = (int*)  w; w += 4*sizeof(int);

  float* psi = (float*)d_out;   // [N,Q]; scalars at NQ..NQ+2

  const size_t small_bytes = (size_t)((char*)w - (char*)deg);
  hipMemsetAsync(deg, 0, small_bytes, stream);   // deg, h, done

  // one-time: h0, CSR build, initial node_log
  k_h_part<<<gN,B,0,stream>>>(psi0, hpart, N);
  k_hfin  <<<1, B,0,stream>>>(hpart, h, betap, gN, mean_w);
  k_deg   <<<gE,B,0,stream>>>(dst, deg, E);
  k_scan1 <<<nb,SCAN_B,0,stream>>>(deg, offs, bsum, N);
  k_scan2 <<<1, SCAN_B,0,stream>>>(bsum, nb);
  k_scan3 <<<nb,SCAN_B,0,stream>>>(offs, cursor, bsum, N, E);
  k_fill  <<<gE,B,0,stream>>>(dst, cursor, eid, E);
  k_gather<<<gW,B,0,stream>>>(msg0, offs, eid, nl, h, psi, betap, donep, hpart, N, 0);

  for (int k=0; k<10; ++k) {
    const float* mc = (k==0) ? msg0 : msgA;
    k_edge   <<<gM,B,0,stream>>>(src, dst, mc, msgA, nl, h, betap, diffpart, donep, M);
    k_gather <<<gW,B,0,stream>>>(msgA, offs, eid, nl, h, psi, betap, donep, hpart, N, 1);
    k_hred   <<<gH,B,0,stream>>>(hpart, gW, hpart2, donep);
    k_iterfin<<<1, B,0,stream>>>(hpart2, gH, diffpart, gM, h, donep, betap, mean_w);
  }

  k_edge_term <<<gM,B,0,stream>>>(src, dst, psi, edgepart, M);
  k_node_stats<<<gN,B,0,stream>>>(psi, deg, colpart, degpart, entpart, N);
  k_finalize  <<<1,B,0,stream>>>(edgepart, gM, colpart, degpart, entpart, gN,
                                 psi, N, m2, NQ);
}

// Round 7
// 1152.864 us; speedup vs baseline: 2.6321x; 1.0656x over previous
//
#include <hip/hip_runtime.h>

#define Q 16
#define SCAN_B 256

__device__ __forceinline__ float wsum(float v){
  #pragma unroll
  for(int o=32;o;o>>=1) v += __shfl_xor(v,o);
  return v;
}
__device__ __forceinline__ float wmaxr(float v){
  #pragma unroll
  for(int o=32;o;o>>=1) v = fmaxf(v,__shfl_xor(v,o));
  return v;
}

// ---- main per-iteration edge kernel: one thread per undirected edge pair ----
// launch_bounds(256,4): VGPR cap 128 so all 20 float4 loads can be in flight
// (at 44 VGPR the compiler serialized loads -> latency chains on random nl reads)
__global__ void __launch_bounds__(256, 4) k_edge(
    const int* __restrict__ src, const int* __restrict__ dst,
    const float* msg_in, float* msg_out,
    const float* __restrict__ nl, const float* __restrict__ hc,
    const float* __restrict__ betap,
    float* __restrict__ diffpart, const int* __restrict__ donep, int M)
{
  if (*donep) return;
  const float eb = __expf(*betap) - 1.0f;
  const int p = blockIdx.x*blockDim.x + threadIdx.x;
  float dloc = 0.0f;
  if (p < M) {
    const int u = src[p], v = dst[p];
    const float4* a  = (const float4*)(msg_in + (size_t)p*Q);
    const float4* b  = (const float4*)(msg_in + ((size_t)p + (size_t)M)*Q);
    const float4* h4 = (const float4*)hc;
    const float4* u4 = (const float4*)(nl + (size_t)u*Q);
    const float4* v4 = (const float4*)(nl + (size_t)v*Q);
    // batch all independent loads up front
    float4 a0=a[0], a1=a[1], a2=a[2], a3=a[3];
    float4 b0=b[0], b1=b[1], b2=b[2], b3=b[3];
    float4 h0=h4[0], h1=h4[1], h2=h4[2], h3=h4[3];
    float4 un0=u4[0], un1=u4[1], un2=u4[2], un3=u4[3];
    float4 vn0=v4[0], vn1=v4[1], vn2=v4[2], vn3=v4[3];
    float muv[Q], mvu[Q], hq[Q], nlu[Q], nlv[Q];
    #define UNP(arr,r0,r1,r2,r3) \
      arr[0]=r0.x;arr[1]=r0.y;arr[2]=r0.z;arr[3]=r0.w; \
      arr[4]=r1.x;arr[5]=r1.y;arr[6]=r1.z;arr[7]=r1.w; \
      arr[8]=r2.x;arr[9]=r2.y;arr[10]=r2.z;arr[11]=r2.w; \
      arr[12]=r3.x;arr[13]=r3.y;arr[14]=r3.z;arr[15]=r3.w;
    UNP(muv,a0,a1,a2,a3) UNP(mvu,b0,b1,b2,b3) UNP(hq,h0,h1,h2,h3)
    UNP(nlu,un0,un1,un2,un3) UNP(nlv,vn0,vn1,vn2,vn3)
    #undef UNP
    float tuv[Q], tvu[Q];
    #pragma unroll
    for (int q=0;q<Q;q++){
      float lsuv = __logf(fmaf(muv[q], eb, 1.0f));   // logS of edge u->v
      float lsvu = __logf(fmaf(mvu[q], eb, 1.0f));   // logS of edge v->u
      tuv[q] = nlu[q] - lsvu + hq[q];                // cavity for u->v removes rev (v->u)
      tvu[q] = nlv[q] - lsuv + hq[q];
    }
    float m1 = tuv[0], m2 = tvu[0];
    #pragma unroll
    for (int q=1;q<Q;q++){ m1=fmaxf(m1,tuv[q]); m2=fmaxf(m2,tvu[q]); }
    float s1=0.0f, s2=0.0f;
    #pragma unroll
    for (int q=0;q<Q;q++){
      tuv[q]=__expf(tuv[q]-m1); s1+=tuv[q];
      tvu[q]=__expf(tvu[q]-m2); s2+=tvu[q];
    }
    const float r1 = 1.0f/s1, r2 = 1.0f/s2;
    float d1=0.0f, d2=0.0f;
    #pragma unroll
    for (int q=0;q<Q;q++){
      float nuv = tuv[q]*r1, nvu = tvu[q]*r2;
      d1 += fabsf(nuv - muv[q]);
      d2 += fabsf(nvu - mvu[q]);
      muv[q]=nuv; mvu[q]=nvu;
    }
    dloc = fmaxf(d1,d2);
    float4* o1 = (float4*)(msg_out + (size_t)p*Q);
    float4* o2 = (float4*)(msg_out + ((size_t)p + (size_t)M)*Q);
    #pragma unroll
    for (int i=0;i<4;i++){
      o1[i] = make_float4(muv[4*i],muv[4*i+1],muv[4*i+2],muv[4*i+3]);
      o2[i] = make_float4(mvu[4*i],mvu[4*i+1],mvu[4*i+2],mvu[4*i+3]);
    }
  }
  // block-level max -> one plain store (no contended atomics)
  __shared__ float smx[4];
  float wm = wmaxr(dloc);
  if ((threadIdx.x & 63) == 0) smx[threadIdx.x>>6] = wm;
  __syncthreads();
  if (threadIdx.x == 0)
    diffpart[blockIdx.x] = fmaxf(fmaxf(smx[0],smx[1]), fmaxf(smx[2],smx[3]));
}

// ---- gather kernel: 4 waves/block, one wave per node; CSR over incoming edges.
// nl[n] = sum_in log1p(msg*eb); mode=1: psi=softmax(nl+h) + per-block h partials.
__global__ void __launch_bounds__(256, 4) k_gather(
    const float* __restrict__ msg, const int* __restrict__ offs,
    const int* __restrict__ eid,
    float* __restrict__ nl, const float* __restrict__ hc,
    float* __restrict__ psi, const float* __restrict__ betap,
    const int* __restrict__ donep, float* __restrict__ hpart,
    int N, int mode)
{
  if (mode && *donep) return;
  const int wid = threadIdx.x >> 6;                 // 0..3
  const int n = blockIdx.x*4 + wid;
  const float eb = __expf(*betap) - 1.0f;
  const int lane = threadIdx.x & 63;
  const int sub = lane >> 4, q = lane & 15;
  int start = 0, end = 0;
  if (n < N){ start = offs[n]; end = offs[n+1]; }
  float acc = 0.0f;
  int i = start + sub;
  // 2x unroll: two independent eid->msg load chains in flight
  for (; i + 4 < end; i += 8){
    const int e0 = eid[i], e1 = eid[i+4];
    const float x0 = msg[(size_t)e0*Q + q];
    const float x1 = msg[(size_t)e1*Q + q];
    acc += __logf(fmaf(x0, eb, 1.0f)) + __logf(fmaf(x1, eb, 1.0f));
  }
  if (i < end)
    acc += __logf(fmaf(msg[(size_t)eid[i]*Q + q], eb, 1.0f));
  acc += __shfl_xor(acc, 16);
  acc += __shfl_xor(acc, 32);
  if (n < N && sub == 0) nl[(size_t)n*Q + q] = acc;
  if (!mode) return;
  float t = acc + hc[q];
  float m = t;
  #pragma unroll
  for (int o=1;o<16;o<<=1) m = fmaxf(m, __shfl_xor(m,o));
  float ex = __expf(t-m);
  float s = ex;
  #pragma unroll
  for (int o=1;o<16;o<<=1) s += __shfl_xor(s,o);
  const float pq = ex/s;
  if (n < N && sub == 0) psi[(size_t)n*Q + q] = pq;
  // per-block h column partials (psi already in registers)
  __shared__ float smh[4][17];
  if (sub == 0) smh[wid][q] = (n < N) ? pq : 0.0f;
  __syncthreads();
  if (threadIdx.x < Q)
    hpart[(size_t)blockIdx.x*Q + threadIdx.x] =
      smh[0][threadIdx.x]+smh[1][threadIdx.x]+smh[2][threadIdx.x]+smh[3][threadIdx.x];
}

// ---- merged per-iteration reduce: hred + (last block) h write + done check ----
__global__ void __launch_bounds__(256) k_hred2(
    const float* __restrict__ hpart, int nrows,
    float* __restrict__ hpart2, int gH,
    const float* __restrict__ diffpart, int nbd,
    float* __restrict__ h, int* __restrict__ donep,
    int* __restrict__ cnt,
    const float* __restrict__ betap, float mean_w)
{
  if (*donep) return;
  const int t = threadIdx.x, g = t>>4, q = t&15;
  __shared__ float sm[16][17];
  {
    const int base = blockIdx.x*256;
    const int lim = min(base+256, nrows);
    float s = 0.0f;
    for (int r = base+g; r < lim; r += 16) s += hpart[(size_t)r*Q + q];
    sm[g][q] = s; __syncthreads();
    if (t < Q){
      float tot = 0.0f;
      #pragma unroll
      for (int i=0;i<16;i++) tot += sm[i][t];
      hpart2[(size_t)blockIdx.x*Q + t] = tot;
    }
  }
  // last block to arrive finishes the reduction
  __shared__ int amLast;
  __threadfence();
  if (t == 0) amLast = (atomicAdd(cnt, 1) == gH-1);
  __syncthreads();
  if (!amLast) return;
  {
    float s = 0.0f;
    for (int b = g; b < gH; b += 16) s += hpart2[(size_t)b*Q + q];
    __syncthreads();
    sm[g][q] = s; __syncthreads();
    if (t < Q){
      float tot = 0.0f;
      #pragma unroll
      for (int i=0;i<16;i++) tot += sm[i][t];
      h[t] = -(*betap) * mean_w * tot;
    }
  }
  float m = 0.0f;
  for (int i = t; i < nbd; i += 256) m = fmaxf(m, diffpart[i]);
  m = wmaxr(m);
  __shared__ float red[4];
  if ((t & 63) == 0) red[t>>6] = m;
  __syncthreads();
  if (t == 0 &&
      fmaxf(fmaxf(red[0],red[1]), fmaxf(red[2],red[3])) < 0.01f) *donep = 1;
}

// ---- h partials over psi0 (init only) ----
__global__ void __launch_bounds__(256) k_h_part(
    const float* __restrict__ psi, float* __restrict__ hpart, int N)
{
  const int n = blockIdx.x*blockDim.x + threadIdx.x;
  float pv[Q];
  if (n < N) {
    const float4* a = (const float4*)(psi + (size_t)n*Q);
    #pragma unroll
    for (int i=0;i<4;i++){ float4 t=a[i]; pv[4*i]=t.x; pv[4*i+1]=t.y; pv[4*i+2]=t.z; pv[4*i+3]=t.w; }
  } else {
    #pragma unroll
    for (int q=0;q<Q;q++) pv[q]=0.0f;
  }
  __shared__ float sm[4][Q];
  const int wid = threadIdx.x>>6, lane = threadIdx.x&63;
  #pragma unroll
  for (int q=0;q<Q;q++){
    float s = wsum(pv[q]);
    if (lane == 0) sm[wid][q] = s;
  }
  __syncthreads();
  if (threadIdx.x < Q)
    hpart[(size_t)blockIdx.x*Q + threadIdx.x] =
      sm[0][threadIdx.x]+sm[1][threadIdx.x]+sm[2][threadIdx.x]+sm[3][threadIdx.x];
}

__global__ void __launch_bounds__(256) k_hfin(
    const float* __restrict__ hpart, float* __restrict__ h,
    const float* __restrict__ betap, int nb, float mean_w)
{
  const int t = threadIdx.x, g = t>>4, q = t&15;
  float s = 0.0f;
  for (int b = g; b < nb; b += 16) s += hpart[(size_t)b*Q + q];
  __shared__ float sm[16][17];
  sm[g][q] = s; __syncthreads();
  if (t < Q){
    float tot = 0.0f;
    #pragma unroll
    for (int i=0;i<16;i++) tot += sm[i][t];
    h[t] = -(*betap) * mean_w * tot;
  }
}

// ---- CSR build ----
__global__ void __launch_bounds__(256) k_deg(
    const int* __restrict__ dst, int* __restrict__ deg, int E)
{
  const int e = blockIdx.x*blockDim.x + threadIdx.x;
  if (e < E) atomicAdd(&deg[dst[e]], 1);
}

__global__ void __launch_bounds__(SCAN_B) k_scan1(
    const int* __restrict__ deg, int* __restrict__ offs,
    int* __restrict__ bsum, int N)
{
  __shared__ int sm[SCAN_B];
  const int i = blockIdx.x*SCAN_B + threadIdx.x;
  const int v = (i<N) ? deg[i] : 0;
  sm[threadIdx.x] = v; __syncthreads();
  #pragma unroll
  for (int o=1;o<SCAN_B;o<<=1){
    int t = (threadIdx.x>=o) ? sm[threadIdx.x-o] : 0;
    __syncthreads();
    sm[threadIdx.x] += t;
    __syncthreads();
  }
  if (i<N) offs[i] = sm[threadIdx.x] - v;           // block-local exclusive
  if (threadIdx.x==SCAN_B-1) bsum[blockIdx.x] = sm[threadIdx.x];
}

__global__ void __launch_bounds__(SCAN_B) k_scan2(int* __restrict__ bsum, int nb)
{
  __shared__ int sm[SCAN_B];
  const int v = (threadIdx.x<nb) ? bsum[threadIdx.x] : 0;
  sm[threadIdx.x] = v; __syncthreads();
  #pragma unroll
  for (int o=1;o<SCAN_B;o<<=1){
    int t = (threadIdx.x>=o) ? sm[threadIdx.x-o] : 0;
    __syncthreads();
    sm[threadIdx.x] += t;
    __syncthreads();
  }
  if (threadIdx.x<nb) bsum[threadIdx.x] = sm[threadIdx.x] - v;  // exclusive
}

__global__ void __launch_bounds__(SCAN_B) k_scan3(
    int* __restrict__ offs, int* __restrict__ cursor,
    const int* __restrict__ bsum, int N, int E)
{
  const int i = blockIdx.x*SCAN_B + threadIdx.x;
  if (i<N){
    const int o = offs[i] + bsum[blockIdx.x];
    offs[i] = o; cursor[i] = o;
  }
  if (i==0) offs[N] = E;
}

__global__ void __launch_bounds__(256) k_fill(
    const int* __restrict__ dst, int* __restrict__ cursor,
    int* __restrict__ eid, int E)
{
  const int e = blockIdx.x*blockDim.x + threadIdx.x;
  if (e < E){
    const int p = atomicAdd(&cursor[dst[e]], 1);
    eid[p] = e;
  }
}

// ---- finalization: per-block partials, no atomics ----
__global__ void __launch_bounds__(256) k_edge_term(
    const int* __restrict__ src, const int* __restrict__ dst,
    const float* __restrict__ psi, float* __restrict__ edgepart, int M)
{
  const int p = blockIdx.x*blockDim.x + threadIdx.x;
  float d = 0.0f;
  if (p < M) {
    const int u = src[p], v = dst[p];
    const float4* a = (const float4*)(psi + (size_t)u*Q);
    const float4* b = (const float4*)(psi + (size_t)v*Q);
    #pragma unroll
    for (int i=0;i<4;i++){
      float4 x=a[i], y=b[i];
      d += x.x*y.x + x.y*y.y + x.z*y.z + x.w*y.w;
    }
    d *= 2.0f;   // each pair appears twice in the directed edge list
  }
  float s = wsum(d);
  __shared__ float sm[4];
  if ((threadIdx.x & 63) == 0) sm[threadIdx.x>>6] = s;
  __syncthreads();
  if (threadIdx.x == 0) edgepart[blockIdx.x] = sm[0]+sm[1]+sm[2]+sm[3];
}

__global__ void __launch_bounds__(256) k_node_stats(
    const float* __restrict__ psi, const int* __restrict__ deg,
    float* __restrict__ colpart, float* __restrict__ degpart,
    float* __restrict__ entpart, int N)
{
  const int n = blockIdx.x*blockDim.x + threadIdx.x;
  float pv[Q]; float dg = 0.0f; float ent = 0.0f;
  if (n < N) {
    const float4* a = (const float4*)(psi + (size_t)n*Q);
    #pragma unroll
    for (int i=0;i<4;i++){ float4 t=a[i]; pv[4*i]=t.x; pv[4*i+1]=t.y; pv[4*i+2]=t.z; pv[4*i+3]=t.w; }
    dg = (float)deg[n];
    #pragma unroll
    for (int q=0;q<Q;q++) ent -= pv[q]*__logf(pv[q]+1e-12f);
  } else {
    #pragma unroll
    for (int q=0;q<Q;q++) pv[q]=0.0f;
  }
  __shared__ float smc[4][Q], smd[4][Q], sme[4];
  const int wid = threadIdx.x>>6, lane = threadIdx.x&63;
  #pragma unroll
  for (int q=0;q<Q;q++){
    float s  = wsum(pv[q]);
    float s2 = wsum(pv[q]*dg);
    if (lane == 0){ smc[wid][q]=s; smd[wid][q]=s2; }
  }
  float se = wsum(ent);
  if (lane == 0) sme[wid] = se;
  __syncthreads();
  if (threadIdx.x < Q){
    colpart[(size_t)blockIdx.x*Q+threadIdx.x] =
      smc[0][threadIdx.x]+smc[1][threadIdx.x]+smc[2][threadIdx.x]+smc[3][threadIdx.x];
    degpart[(size_t)blockIdx.x*Q+threadIdx.x] =
      smd[0][threadIdx.x]+smd[1][threadIdx.x]+smd[2][threadIdx.x]+smd[3][threadIdx.x];
  }
  if (threadIdx.x == 0) entpart[blockIdx.x] = sme[0]+sme[1]+sme[2]+sme[3];
}

__global__ void __launch_bounds__(256) k_finalize(
    const float* __restrict__ edgepart, int ne,
    const float* __restrict__ colpart, const float* __restrict__ degpart,
    const float* __restrict__ entpart, int nbn,
    float* __restrict__ out, int N, float m2, int NQ)
{
  __shared__ float sm[16][Q];
  __shared__ float red[4];
  const int t = threadIdx.x, g = t>>4, q = t&15;
  float cs=0.0f, ds=0.0f;
  for (int b=g; b<nbn; b+=16){ cs += colpart[(size_t)b*Q+q]; ds += degpart[(size_t)b*Q+q]; }
  sm[g][q] = cs; __syncthreads();
  float colq = 0.0f;
  if (t < Q){ for (int i=0;i<16;i++) colq += sm[i][t]; }
  __syncthreads();
  sm[g][q] = ds; __syncthreads();
  float degq = 0.0f;
  if (t < Q){ for (int i=0;i<16;i++) degq += sm[i][t]; }
  __syncthreads();
  float es = 0.0f;
  for (int i=t; i<ne; i+=256) es += edgepart[i];
  es = wsum(es);
  if ((t&63)==0) red[t>>6] = es;
  __syncthreads();
  const float edge_total = red[0]+red[1]+red[2]+red[3];
  __syncthreads();
  float en = 0.0f;
  for (int i=t; i<nbn; i+=256) en += entpart[i];
  en = wsum(en);
  if ((t&63)==0) red[t>>6] = en;
  __syncthreads();
  const float ent_total = red[0]+red[1]+red[2]+red[3];
  __syncthreads();
  if (t < Q){ sm[0][t] = colq; sm[1][t] = degq; }
  __syncthreads();
  if (t == 0){
    float reg = 0.0f, dt = 0.0f;
    for (int i=0;i<Q;i++){
      float d = sm[0][i]/(float)N - 1.0f/(float)Q; reg += d*d;
      float s = sm[1][i]/m2; dt += s*s;
    }
    out[NQ+0] = reg * 4.0f;                                // * sqrt(16)
    out[NQ+1] = ent_total/(float)N / 2.7725887222397811f;  // / log(16)
    out[NQ+2] = edge_total/m2 - dt;
  }
}

extern "C" void kernel_launch(void* const* d_in, const int* in_sizes, int n_in,
                              void* d_out, int out_size, void* d_ws, size_t ws_size,
                              hipStream_t stream)
{
  const int*   src   = (const int*)  d_in[0];
  const int*   dst   = (const int*)  d_in[1];
  // d_in[2] = rev : structurally rev[p]=p+M / p-M, exploited directly
  const float* psi0  = (const float*)d_in[3];
  const float* msg0  = (const float*)d_in[4];
  const float* betap = (const float*)d_in[5];

  const int E  = in_sizes[0];
  const int M  = E/2;
  const int NQ = in_sizes[3];
  const int N  = NQ/Q;
  const float mean_w = (float)((double)E/((double)N*(double)N));
  const float m2 = (float)E;

  const int B = 256;
  const int gE = (E+B-1)/B, gM = (M+B-1)/B, gN = (N+B-1)/B;
  const int nb = (N+SCAN_B-1)/SCAN_B;
  const int gW = (N+3)/4;                        // 4 nodes per 256-thr block
  const int gH = (gW+255)/256;                   // hred blocks (~49)

  char* w = (char*)d_ws;
  float* msgA    = (float*)w; w += (size_t)E*Q*sizeof(float);
  float* nl      = (float*)w; w += (size_t)NQ*sizeof(float);
  int*   eid     = (int*)  w; w += (size_t)E*sizeof(int);
  int*   offs    = (int*)  w; w += (size_t)(N+16)*sizeof(int);
  int*   cursor  = (int*)  w; w += (size_t)(N+16)*sizeof(int);
  int*   bsum    = (int*)  w; w += 256*sizeof(int);
  float* hpart   = (float*)w; w += (size_t)gW*Q*sizeof(float);   // also init partials (gN<gW)
  float* hpart2  = (float*)w; w += (size_t)gH*Q*sizeof(float);
  float* diffpart= (float*)w; w += (size_t)gM*sizeof(float);
  float* edgepart= (float*)w; w += (size_t)gM*sizeof(float);
  float* colpart = (float*)w; w += (size_t)gN*Q*sizeof(float);
  float* degpart = (float*)w; w += (size_t)gN*Q*sizeof(float);
  float* entpart = (float*)w; w += (size_t)gN*sizeof(float);
  int*   deg     = (int*)  w; w += (size_t)(N+16)*sizeof(int);   // memset from here
  float* h       = (float*)w; w += 16*sizeof(float);
  int*   donep   = (int*)  w; w += 4*sizeof(int);
  int*   cnt     = (int*)  w; w += 16*sizeof(int);               // per-iter arrival counters

  float* psi = (float*)d_out;   // [N,Q]; scalars at NQ..NQ+2

  const size_t small_bytes = (size_t)((char*)w - (char*)deg);
  hipMemsetAsync(deg, 0, small_bytes, stream);   // deg, h, done, cnt

  // one-time: h0, CSR build, initial node_log
  k_h_part<<<gN,B,0,stream>>>(psi0, hpart, N);
  k_hfin  <<<1, B,0,stream>>>(hpart, h, betap, gN, mean_w);
  k_deg   <<<gE,B,0,stream>>>(dst, deg, E);
  k_scan1 <<<nb,SCAN_B,0,stream>>>(deg, offs, bsum, N);
  k_scan2 <<<1, SCAN_B,0,stream>>>(bsum, nb);
  k_scan3 <<<nb,SCAN_B,0,stream>>>(offs, cursor, bsum, N, E);
  k_fill  <<<gE,B,0,stream>>>(dst, cursor, eid, E);
  k_gather<<<gW,B,0,stream>>>(msg0, offs, eid, nl, h, psi, betap, donep, hpart, N, 0);

  for (int k=0; k<10; ++k) {
    const float* mc = (k==0) ? msg0 : msgA;
    k_edge  <<<gM,B,0,stream>>>(src, dst, mc, msgA, nl, h, betap, diffpart, donep, M);
    k_gather<<<gW,B,0,stream>>>(msgA, offs, eid, nl, h, psi, betap, donep, hpart, N, 1);
    k_hred2 <<<gH,B,0,stream>>>(hpart, gW, hpart2, gH, diffpart, gM,
                                h, donep, &cnt[k], betap, mean_w);
  }

  k_edge_term <<<gM,B,0,stream>>>(src, dst, psi, edgepart, M);
  k_node_stats<<<gN,B,0,stream>>>(psi, deg, colpart, degpart, entpart, N);
  k_finalize  <<<1,B,0,stream>>>(edgepart, gM, colpart, degpart, entpart, gN,
                                 psi, N, m2, NQ);
}